// Round 15
// baseline (77.775 us; speedup 1.0000x reference)
//
#include <hip/hip_runtime.h>
#include <math.h>

#define NROWS 8192
#define DIM 512
#define INV_T 20.0f
#define QS 500.0f
// dequant * 1/T * log2(e), for exp2-based softmax accumulation
#define DEQ2 (INV_T * 1.4426950408889634f / (QS * QS))

typedef __attribute__((ext_vector_type(4))) int i32x4;

__device__ __forceinline__ void gload_lds16(const void* g, void* l) {
    __builtin_amdgcn_global_load_lds(
        (const __attribute__((address_space(1))) unsigned int*)g,
        (__attribute__((address_space(3))) unsigned int*)l, 16, 0, 0);
}

__device__ __forceinline__ void block_bar() {
    asm volatile("" ::: "memory");
    __builtin_amdgcn_s_barrier();
    asm volatile("" ::: "memory");
}

__device__ __forceinline__ float hw_exp2(float x) {
    float r;
    asm("v_exp_f32 %0, %1" : "=v"(r) : "v"(x));  // D = 2^S0, 1 inst
    return r;
}

__device__ __forceinline__ float dot4(float4 a, float4 b) {
    return a.x * b.x + a.y * b.y + a.z * b.z + a.w * b.w;
}

__device__ __forceinline__ int q4(float4 v, float s) {
    int b0 = __float2int_rn(fminf(fmaxf(v.x * s, -127.f), 127.f)) & 255;
    int b1 = __float2int_rn(fminf(fmaxf(v.y * s, -127.f), 127.f)) & 255;
    int b2 = __float2int_rn(fminf(fmaxf(v.z * s, -127.f), 127.f)) & 255;
    int b3 = __float2int_rn(fminf(fmaxf(v.w * s, -127.f), 127.f)) & 255;
    return b0 | (b1 << 8) | (b2 << 16) | (b3 << 24);
}

// One wave per row: L2-normalize, quantize to i8 (scale QS), exact fp32 diag,
// column log2-weights (0 or 1), zero row-sum accumulator.
__global__ __launch_bounds__(256) void norm_kernel(
    const float* __restrict__ A, const float* __restrict__ S,
    const int* __restrict__ labels, signed char* __restrict__ aQ,
    signed char* __restrict__ sQ, float* __restrict__ diag,
    float* __restrict__ lw2, float* __restrict__ lsum) {
    const int wave = threadIdx.x >> 6, lane = threadIdx.x & 63;
    const int row = blockIdx.x * 4 + wave;
    const float4* a4 = (const float4*)(A + (size_t)row * DIM);
    const float4* s4 = (const float4*)(S + (size_t)row * DIM);
    float4 a0 = a4[lane], a1 = a4[lane + 64];
    float4 s0 = s4[lane], s1 = s4[lane + 64];
    float saa = dot4(a0, a0) + dot4(a1, a1);
    float sss = dot4(s0, s0) + dot4(s1, s1);
    float sas = dot4(a0, s0) + dot4(a1, s1);
    for (int m = 1; m < 64; m <<= 1) {
        saa += __shfl_xor(saa, m);
        sss += __shfl_xor(sss, m);
        sas += __shfl_xor(sas, m);
    }
    const float ra = rsqrtf(saa), rs = rsqrtf(sss);
    signed char* arow = aQ + (size_t)row * DIM;
    signed char* srow = sQ + (size_t)row * DIM;
    *(int*)(arow + lane * 4)       = q4(a0, ra * QS);
    *(int*)(arow + 256 + lane * 4) = q4(a1, ra * QS);
    *(int*)(srow + lane * 4)       = q4(s0, rs * QS);
    *(int*)(srow + 256 + lane * 4) = q4(s1, rs * QS);
    if (lane == 0) {
        diag[row] = sas * ra * rs * INV_T;
        // Uniform column weighting (incl. diagonal) is exact for the final
        // loss: only label==1 rows' lse is consumed, and those rows' diagonal
        // column has log_w==0 in the reference anyway. log2-weight: 0 or 1.
        lw2[row] = (labels[row] == 0) ? 1.0f : 0.0f;
        lsum[row] = 0.0f;
    }
}

// ---------------------------------------------------------------------------
// Full 8-phase-template i8 GEMM + exp2 + row-sum (v15).
// Template-faithful geometry: block tile 256x256, 8 waves 2M x 4N (wave =
// 128x64, acc 8x4 frags = 128 VGPR), ct-sweep x4 -> 32 K-tiles (BK=64).
// 3-deep LDS buffering (3 x 32 KB = 96 KB), staging 2-tiles-ahead.
// Per K-tile: 4 phases, each {ds_read subtile + stage 1 gload -> barrier ->
// lgkmcnt(0) -> sched_barrier -> setprio(1) 8 MFMA setprio(0) -> barrier};
// vmcnt(4) ONCE per K-tile (ph3; counted = T+2's 4 in-flight loads; drains
// to 0 only at T=30). Quadrant order Q00->Q01->Q11->Q10 for operand
// liveness. Grid 256 = 1 block/CU, 2D XCD map (~3 MB/XCD).
// Swizzles: r3/r4-verified 4-slot involution, both sides.
// ---------------------------------------------------------------------------
__global__ __launch_bounds__(512, 2) void lse_gemm(
    const signed char* __restrict__ Aq, const signed char* __restrict__ Bq,
    const float* __restrict__ lw2, float* __restrict__ lsum) {
    __shared__ __align__(16) char lds[98304];  // 3 bufs x 32 KB (A 16K, B 16K)

    const int bid = blockIdx.x;  // 256 blocks = 1 per CU
    const int xcd = bid & 7, idx = bid >> 3;    // bid%8 -> XCD
    const int rt = (xcd & 3) * 8 + (idx & 7);   // 0..31 (256-row tile)
    const int ctg = (xcd >> 2) * 4 + (idx >> 3);  // 0..7 (1024-col group)
    const int row0 = rt * 256;
    const int colg = ctg * 1024;

    const int tid = threadIdx.x;
    const int wid = tid >> 6, lane = tid & 63;
    const int wr = wid >> 2, wc = wid & 3;  // 2M x 4N; wave = 128 x 64
    const int fr = lane & 15, grp = lane >> 4;

    // staging: thread t -> row t>>2 (0..127) of a 128-row chunk, phys slot
    // t&3; fetch logical slot (t&3)^((t>>3)&3)  [4-slot involution, verified]
    const int sl = (tid & 3) ^ ((tid >> 3) & 3);
    const signed char* aS = Aq + (size_t)(row0 + (tid >> 2)) * DIM + sl * 16;
    const signed char* bS = Bq + (size_t)(colg + (tid >> 2)) * DIM + sl * 16;
    char* dst = lds + tid * 16;

    // K-tile TT (0..31): ct = TT>>3, k = TT&7. One 8 KB staging round r:
    // r0/r1 = A chunks 0/1, r2/r3 = B chunks 0/1.
#define STG(buf, TT, r)                                                       \
    do {                                                                      \
        if ((r) < 2)                                                          \
            gload_lds16(aS + (r) * 65536 + ((TT) & 7) * 64,                   \
                        dst + (buf) * 32768 + (r) * 8192);                    \
        else                                                                  \
            gload_lds16(bS + ((TT) >> 3) * 131072 + ((r) - 2) * 65536 +       \
                            ((TT) & 7) * 64,                                  \
                        dst + (buf) * 32768 + 16384 + ((r) - 2) * 8192);      \
    } while (0)

    // fragment reads: A row R = wr*128 + m*16 + fr at byte R*64 + ps;
    // B row = wc*64 + n*16 + fr at +16384. ps = (grp ^ ((fr>>1)&3))*16.
    const int ps = (grp ^ ((fr >> 1) & 3)) << 4;
    const char* rdA = lds + (wr * 128 + fr) * 64 + ps;
    const char* rdB = lds + 16384 + (wc * 64 + fr) * 64 + ps;

    // ---- prologue: tiles 0,1 fully staged; tile 0 complete before loop
    STG(0, 0, 0); STG(0, 0, 1); STG(0, 0, 2); STG(0, 0, 3);
    STG(1, 1, 0); STG(1, 1, 1); STG(1, 1, 2); STG(1, 1, 3);
    asm volatile("s_waitcnt vmcnt(4)" ::: "memory");
    block_bar();

    i32x4 aLo[4], aHi[4], b[4];
    i32x4 acc[8][4] = {};

#pragma unroll 1
    for (int T = 0; T < 32; ++T) {
        const int buf = T % 3;
        const int bufS = (T + 2) % 3;  // staging dest (tile T+2)
        const int pf = (T + 2 < 32);

        // ---- phase 0: read a[m0-3] + b[n0-1]; stage r0; MFMA Q00
#pragma unroll
        for (int m = 0; m < 4; ++m)
            aLo[m] = *(const i32x4*)(rdA + buf * 32768 + m * 1024);
#pragma unroll
        for (int n = 0; n < 2; ++n)
            b[n] = *(const i32x4*)(rdB + buf * 32768 + n * 1024);
        if (pf) STG(bufS, T + 2, 0);
        block_bar();
        asm volatile("s_waitcnt lgkmcnt(0)" ::: "memory");
        __builtin_amdgcn_sched_barrier(0);
        __builtin_amdgcn_s_setprio(1);
#pragma unroll
        for (int m = 0; m < 4; ++m)
#pragma unroll
            for (int n = 0; n < 2; ++n)
                acc[m][n] = __builtin_amdgcn_mfma_i32_16x16x64_i8(
                    aLo[m], b[n], acc[m][n], 0, 0, 0);
        __builtin_amdgcn_s_setprio(0);
        block_bar();

        // ---- phase 1: read b[n2-3]; stage r1; MFMA Q01
#pragma unroll
        for (int n = 2; n < 4; ++n)
            b[n] = *(const i32x4*)(rdB + buf * 32768 + n * 1024);
        if (pf) STG(bufS, T + 2, 1);
        block_bar();
        asm volatile("s_waitcnt lgkmcnt(0)" ::: "memory");
        __builtin_amdgcn_sched_barrier(0);
        __builtin_amdgcn_s_setprio(1);
#pragma unroll
        for (int m = 0; m < 4; ++m)
#pragma unroll
            for (int n = 2; n < 4; ++n)
                acc[m][n] = __builtin_amdgcn_mfma_i32_16x16x64_i8(
                    aLo[m], b[n], acc[m][n], 0, 0, 0);
        __builtin_amdgcn_s_setprio(0);
        block_bar();

        // ---- phase 2: read a[m4-7]; stage r2; MFMA Q11
#pragma unroll
        for (int m = 0; m < 4; ++m)
            aHi[m] = *(const i32x4*)(rdA + buf * 32768 + 4096 + m * 1024);
        if (pf) STG(bufS, T + 2, 2);
        block_bar();
        asm volatile("s_waitcnt lgkmcnt(0)" ::: "memory");
        __builtin_amdgcn_sched_barrier(0);
        __builtin_amdgcn_s_setprio(1);
#pragma unroll
        for (int m = 0; m < 4; ++m)
#pragma unroll
            for (int n = 2; n < 4; ++n)
                acc[m + 4][n] = __builtin_amdgcn_mfma_i32_16x16x64_i8(
                    aHi[m], b[n], acc[m + 4][n], 0, 0, 0);
        __builtin_amdgcn_s_setprio(0);
        block_bar();

        // ---- phase 3: stage r3; counted vmcnt (once per K-tile); MFMA Q10
        if (pf) STG(bufS, T + 2, 3);
        if (T <= 29)
            asm volatile("s_waitcnt vmcnt(4)" ::: "memory");  // T+1 retired
        else
            asm volatile("s_waitcnt vmcnt(0)" ::: "memory");  // tail drain
        block_bar();
        __builtin_amdgcn_s_setprio(1);
#pragma unroll
        for (int m = 0; m < 4; ++m)
#pragma unroll
            for (int n = 0; n < 2; ++n)
                acc[m + 4][n] = __builtin_amdgcn_mfma_i32_16x16x64_i8(
                    aHi[m], b[n], acc[m + 4][n], 0, 0, 0);
        __builtin_amdgcn_s_setprio(0);
        block_bar();

        if ((T & 7) == 7) {
            // per-ct epilogue (register-lean, in-cage): dequant -> exp2 ->
            // 16-lane reduce -> atomicAdd; then re-zero acc.
            const int ct = T >> 3;
            const int col0 = colg + ct * 256 + wc * 64;
            float lwv[4];
#pragma unroll
            for (int n = 0; n < 4; ++n)
                lwv[n] = lw2[col0 + n * 16 + fr];
#pragma unroll
            for (int m = 0; m < 8; ++m)
#pragma unroll
                for (int j = 0; j < 4; ++j) {
                    float s = 0.f;
#pragma unroll
                    for (int n = 0; n < 4; ++n)
                        s += hw_exp2(fmaf((float)acc[m][n][j], DEQ2, lwv[n]));
                    s += __shfl_xor(s, 1);
                    s += __shfl_xor(s, 2);
                    s += __shfl_xor(s, 4);
                    s += __shfl_xor(s, 8);
                    if (fr == 0)
                        atomicAdd(&lsum[row0 + wr * 128 + m * 16 + grp * 4 + j], s);
                }
#pragma unroll
            for (int m = 0; m < 8; ++m)
#pragma unroll
                for (int n = 0; n < 4; ++n)
                    acc[m][n] = i32x4{0, 0, 0, 0};
        }
    }
#undef STG
}

// 1024 threads, single block: final scalar reduction.
__global__ __launch_bounds__(1024) void finalize_kernel(
    const float* __restrict__ lsum, const float* __restrict__ diag,
    const int* __restrict__ labels, float* __restrict__ out) {
    const int tid = threadIdx.x;
    float sl = 0.f, sd = 0.f, mx = -1e9f;
    int np_ = 0, nn_ = 0;
#pragma unroll
    for (int i = tid; i < NROWS; i += 1024) {
        const float dg = diag[i];
        if (labels[i] == 1) {
            sl += logf(lsum[i]) - dg;
            sd += dg;
            np_++;
        } else {
            nn_++;
            mx = fmaxf(mx, dg);
        }
    }
    for (int m = 1; m < 64; m <<= 1) {
        sl += __shfl_xor(sl, m);
        sd += __shfl_xor(sd, m);
        mx = fmaxf(mx, __shfl_xor(mx, m));
        np_ += __shfl_xor(np_, m);
        nn_ += __shfl_xor(nn_, m);
    }
    __shared__ float rsl[16], rsd[16], rmx[16];
    __shared__ int rnp[16], rnn[16];
    const int wave = tid >> 6, lane = tid & 63;
    if (lane == 0) {
        rsl[wave] = sl; rsd[wave] = sd; rmx[wave] = mx;
        rnp[wave] = np_; rnn[wave] = nn_;
    }
    __syncthreads();
    if (tid == 0) {
        float SL = 0.f, SD = 0.f, MX = -1e9f;
        int NP = 0, NN = 0;
        for (int w = 0; w < 16; w++) {
            SL += rsl[w]; SD += rsd[w]; MX = fmaxf(MX, rmx[w]);
            NP += rnp[w]; NN += rnn[w];
        }
        const float infonce = SL / (float)NP;
        const float meanpos = SD / (float)NP;
        float pen = fmaxf(MX - meanpos + 0.2f, 0.0f);
        if (NN == 0) pen = 0.0f;
        out[0] = infonce + pen;
    }
}

extern "C" void kernel_launch(void* const* d_in, const int* in_sizes, int n_in,
                              void* d_out, int out_size, void* d_ws, size_t ws_size,
                              hipStream_t stream) {
    const float* A = (const float*)d_in[0];
    const float* S = (const float*)d_in[1];
    const int* labels = (const int*)d_in[2];
    float* out = (float*)d_out;

    char* ws = (char*)d_ws;
    signed char* aQ = (signed char*)ws;                          // 4 MB
    signed char* sQ = (signed char*)(ws + (size_t)NROWS * DIM);  // 4 MB
    char* p = ws + (size_t)NROWS * DIM * 2;
    float* diag = (float*)p;                // 32 KB
    float* lw2 = (float*)(p + 32768);       // 32 KB
    float* lsum = (float*)(p + 65536);      // 32 KB

    norm_kernel<<<NROWS / 4, 256, 0, stream>>>(A, S, labels, aQ, sQ, diag, lw2, lsum);
    lse_gemm<<<256, 512, 0, stream>>>(aQ, sQ, lw2, lsum);
    finalize_kernel<<<1, 1024, 0, stream>>>(lsum, diag, labels, out);
}

// Round 16
// 66.841 us; speedup vs baseline: 1.1636x; 1.1636x over previous
//
#include <hip/hip_runtime.h>
#include <math.h>

#define NROWS 8192
#define DIM 512
#define INV_T 20.0f
#define QS 500.0f
// dequant * 1/T * log2(e), for exp2-based softmax accumulation
#define DEQ2 (INV_T * 1.4426950408889634f / (QS * QS))

typedef __attribute__((ext_vector_type(4))) int i32x4;

__device__ __forceinline__ void gload_lds16(const void* g, void* l) {
    __builtin_amdgcn_global_load_lds(
        (const __attribute__((address_space(1))) unsigned int*)g,
        (__attribute__((address_space(3))) unsigned int*)l, 16, 0, 0);
}

__device__ __forceinline__ void block_bar() {
    asm volatile("" ::: "memory");
    __builtin_amdgcn_s_barrier();
    asm volatile("" ::: "memory");
}

__device__ __forceinline__ float hw_exp2(float x) {
    float r;
    asm("v_exp_f32 %0, %1" : "=v"(r) : "v"(x));  // D = 2^S0, 1 inst
    return r;
}

__device__ __forceinline__ float dot4(float4 a, float4 b) {
    return a.x * b.x + a.y * b.y + a.z * b.z + a.w * b.w;
}

__device__ __forceinline__ int q4(float4 v, float s) {
    int b0 = __float2int_rn(fminf(fmaxf(v.x * s, -127.f), 127.f)) & 255;
    int b1 = __float2int_rn(fminf(fmaxf(v.y * s, -127.f), 127.f)) & 255;
    int b2 = __float2int_rn(fminf(fmaxf(v.z * s, -127.f), 127.f)) & 255;
    int b3 = __float2int_rn(fminf(fmaxf(v.w * s, -127.f), 127.f)) & 255;
    return b0 | (b1 << 8) | (b2 << 16) | (b3 << 24);
}

// One wave per row: L2-normalize, quantize to i8 (scale QS), exact fp32 diag,
// column log2-weights (0 or 1), zero row-sum accumulator.
__global__ __launch_bounds__(256) void norm_kernel(
    const float* __restrict__ A, const float* __restrict__ S,
    const int* __restrict__ labels, signed char* __restrict__ aQ,
    signed char* __restrict__ sQ, float* __restrict__ diag,
    float* __restrict__ lw2, float* __restrict__ lsum) {
    const int wave = threadIdx.x >> 6, lane = threadIdx.x & 63;
    const int row = blockIdx.x * 4 + wave;
    const float4* a4 = (const float4*)(A + (size_t)row * DIM);
    const float4* s4 = (const float4*)(S + (size_t)row * DIM);
    float4 a0 = a4[lane], a1 = a4[lane + 64];
    float4 s0 = s4[lane], s1 = s4[lane + 64];
    float saa = dot4(a0, a0) + dot4(a1, a1);
    float sss = dot4(s0, s0) + dot4(s1, s1);
    float sas = dot4(a0, s0) + dot4(a1, s1);
    for (int m = 1; m < 64; m <<= 1) {
        saa += __shfl_xor(saa, m);
        sss += __shfl_xor(sss, m);
        sas += __shfl_xor(sas, m);
    }
    const float ra = rsqrtf(saa), rs = rsqrtf(sss);
    signed char* arow = aQ + (size_t)row * DIM;
    signed char* srow = sQ + (size_t)row * DIM;
    *(int*)(arow + lane * 4)       = q4(a0, ra * QS);
    *(int*)(arow + 256 + lane * 4) = q4(a1, ra * QS);
    *(int*)(srow + lane * 4)       = q4(s0, rs * QS);
    *(int*)(srow + 256 + lane * 4) = q4(s1, rs * QS);
    if (lane == 0) {
        diag[row] = sas * ra * rs * INV_T;
        // Uniform column weighting (incl. diagonal) is exact for the final
        // loss: only label==1 rows' lse is consumed, and those rows' diagonal
        // column has log_w==0 in the reference anyway. log2-weight: 0 or 1.
        lw2[row] = (labels[row] == 0) ? 1.0f : 0.0f;
        lsum[row] = 0.0f;
    }
}

// ---------------------------------------------------------------------------
// Phased i8 GEMM + exp2 + row-sum (v16 = r12 with 3-DEEP staging pipeline).
// Single-variable change vs r12 (51 us): 3 LDS buffers (72 KB, still exactly
// 2 blocks/CU), stage K-step T+2 at the top of step T, counted vmcnt(6)
// (waits only for T's 3 loads; T+1 and T+2 remain in flight). Hypothesis
// from the r4-r15 model fit: all prior designs had exactly 1 step of
// staging lookahead, and the per-step wall tracks the exposed load chain at
// depth 1 (r7 barrier-free same wall; LDS BW at 18%; barriers exonerated).
// WAR: buf (T+2)%3 was last read at step T-1, whose reads-done barrier
// precedes this staging. Tail: T=30 -> vmcnt(3), T=31 -> vmcnt(0).
// Geometry/swizzles/epilogue byte-identical to r12.
// ---------------------------------------------------------------------------
__global__ __launch_bounds__(512, 4) void lse_gemm(
    const signed char* __restrict__ Aq, const signed char* __restrict__ Bq,
    const float* __restrict__ lw2, float* __restrict__ lsum) {
    __shared__ __align__(16) char lds[73728];
    // 3 bufs (stride 24576): A 16 KB @0, B 8 KB @16384

    const int bid = blockIdx.x;  // 512 blocks = 2 per CU
    const int xcd = bid & 7, idx = bid >> 3;     // bid%8 -> XCD
    const int rt = (xcd >> 1) * 8 + (idx & 7);   // 0..31 (256-row tile)
    const int ctg = (xcd & 1) * 8 + (idx >> 3);  // 0..15 (512-col group)
    const int row0 = rt * 256;
    const int colg = ctg * 512;

    const int tid = threadIdx.x;
    const int wid = tid >> 6, lane = tid & 63;
    const int wr = wid >> 1, wc = wid & 1;  // 4x2 wave grid (64x64 each)
    const int fr = lane & 15, grp = lane >> 4;

    // staging: thread t -> row t>>2 (A also +128 via second load), phys slot
    // t&3; fetch logical slot (t&3)^((t>>3)&3)  [4-slot involution, verified]
    const int sl = (tid & 3) ^ ((tid >> 3) & 3);
    const signed char* aSrc = Aq + (size_t)(row0 + (tid >> 2)) * DIM + sl * 16;
    const signed char* bSrc = Bq + (size_t)(colg + (tid >> 2)) * DIM + sl * 16;
    char* dstA = lds + tid * 16;          // + buf*24576 (+8192 for rows 128+)
    char* dstB = lds + 16384 + tid * 16;  // + buf*24576

    // K-step TT (0..31): ct = TT>>3, k = TT&7. 3 loads per thread per step.
#define STAGE(buf, TT)                                                        \
    do {                                                                      \
        const int ct_ = (TT) >> 3, k_ = (TT) & 7;                             \
        gload_lds16(aSrc + k_ * 64,               dstA + (buf) * 24576);      \
        gload_lds16(aSrc + 65536 + k_ * 64,       dstA + (buf) * 24576 + 8192); \
        gload_lds16(bSrc + ct_ * 65536 + k_ * 64, dstB + (buf) * 24576);      \
    } while (0)

    // fragment reads: A row R = wr*64 + m*16 + fr at byte R*64 + ps;
    // B row = wc*64 + n*16 + fr. ps = (grp ^ ((fr>>1)&3))*16.
    const int ps = (grp ^ ((fr >> 1) & 3)) << 4;
    const char* rdA = lds + (wr * 64 + fr) * 64 + ps;
    const char* rdB = lds + 16384 + (wc * 64 + fr) * 64 + ps;

    // ---- prologue: steps 0 and 1 staged; step 2 staged at loop top T=0
    STAGE(0, 0);
    STAGE(1, 1);

    i32x4 acc[4][4] = {};
#pragma unroll 2
    for (int T = 0; T < 32; ++T) {
        const int buf = T % 3;
        if (T < 30) {
            STAGE((T + 2) % 3, T + 2);
            // outstanding <= 9 (T,T+1,T+2); retire T's 3 -> data ready
            asm volatile("s_waitcnt vmcnt(6)" ::: "memory");
        } else if (T == 30) {
            asm volatile("s_waitcnt vmcnt(3)" ::: "memory");
        } else {
            asm volatile("s_waitcnt vmcnt(0)" ::: "memory");
        }
        block_bar();  // buf(T) staged by all waves

        i32x4 a[4], b[4];
#pragma unroll
        for (int m = 0; m < 4; ++m)
            a[m] = *(const i32x4*)(rdA + buf * 24576 + m * 1024);
#pragma unroll
        for (int n = 0; n < 4; ++n)
            b[n] = *(const i32x4*)(rdB + buf * 24576 + n * 1024);
        asm volatile("s_waitcnt lgkmcnt(0)" ::: "memory");
        __builtin_amdgcn_sched_barrier(0);  // rule 18: pin MFMA after lgkm

        __builtin_amdgcn_s_setprio(1);
#pragma unroll
        for (int m = 0; m < 4; ++m)
#pragma unroll
            for (int n = 0; n < 4; ++n)
                acc[m][n] = __builtin_amdgcn_mfma_i32_16x16x64_i8(
                    a[m], b[n], acc[m][n], 0, 0, 0);
        __builtin_amdgcn_s_setprio(0);

        if ((T & 7) == 7) {
            // register-lean in-cage epilogue (r10/r12-proven): dequant ->
            // exp2 -> 16-lane reduce -> atomicAdd; other block covers it.
            const int ct = T >> 3;
            const int col0 = colg + ct * 128 + wc * 64;
            float lwv[4];
#pragma unroll
            for (int n = 0; n < 4; ++n)
                lwv[n] = lw2[col0 + n * 16 + fr];
#pragma unroll
            for (int m = 0; m < 4; ++m)
#pragma unroll
                for (int j = 0; j < 4; ++j) {
                    float s = 0.f;
#pragma unroll
                    for (int n = 0; n < 4; ++n)
                        s += hw_exp2(fmaf((float)acc[m][n][j], DEQ2, lwv[n]));
                    s += __shfl_xor(s, 1);
                    s += __shfl_xor(s, 2);
                    s += __shfl_xor(s, 4);
                    s += __shfl_xor(s, 8);
                    if (fr == 0)
                        atomicAdd(&lsum[row0 + wr * 64 + m * 16 + grp * 4 + j], s);
                }
#pragma unroll
            for (int m = 0; m < 4; ++m)
#pragma unroll
                for (int n = 0; n < 4; ++n)
                    acc[m][n] = i32x4{0, 0, 0, 0};
        }
        block_bar();  // buf(T) reads done before it is re-staged (T+3)
    }
#undef STAGE
}

// 1024 threads, single block: final scalar reduction.
__global__ __launch_bounds__(1024) void finalize_kernel(
    const float* __restrict__ lsum, const float* __restrict__ diag,
    const int* __restrict__ labels, float* __restrict__ out) {
    const int tid = threadIdx.x;
    float sl = 0.f, sd = 0.f, mx = -1e9f;
    int np_ = 0, nn_ = 0;
#pragma unroll
    for (int i = tid; i < NROWS; i += 1024) {
        const float dg = diag[i];
        if (labels[i] == 1) {
            sl += logf(lsum[i]) - dg;
            sd += dg;
            np_++;
        } else {
            nn_++;
            mx = fmaxf(mx, dg);
        }
    }
    for (int m = 1; m < 64; m <<= 1) {
        sl += __shfl_xor(sl, m);
        sd += __shfl_xor(sd, m);
        mx = fmaxf(mx, __shfl_xor(mx, m));
        np_ += __shfl_xor(np_, m);
        nn_ += __shfl_xor(nn_, m);
    }
    __shared__ float rsl[16], rsd[16], rmx[16];
    __shared__ int rnp[16], rnn[16];
    const int wave = tid >> 6, lane = tid & 63;
    if (lane == 0) {
        rsl[wave] = sl; rsd[wave] = sd; rmx[wave] = mx;
        rnp[wave] = np_; rnn[wave] = nn_;
    }
    __syncthreads();
    if (tid == 0) {
        float SL = 0.f, SD = 0.f, MX = -1e9f;
        int NP = 0, NN = 0;
        for (int w = 0; w < 16; w++) {
            SL += rsl[w]; SD += rsd[w]; MX = fmaxf(MX, rmx[w]);
            NP += rnp[w]; NN += rnn[w];
        }
        const float infonce = SL / (float)NP;
        const float meanpos = SD / (float)NP;
        float pen = fmaxf(MX - meanpos + 0.2f, 0.0f);
        if (NN == 0) pen = 0.0f;
        out[0] = infonce + pen;
    }
}

extern "C" void kernel_launch(void* const* d_in, const int* in_sizes, int n_in,
                              void* d_out, int out_size, void* d_ws, size_t ws_size,
                              hipStream_t stream) {
    const float* A = (const float*)d_in[0];
    const float* S = (const float*)d_in[1];
    const int* labels = (const int*)d_in[2];
    float* out = (float*)d_out;

    char* ws = (char*)d_ws;
    signed char* aQ = (signed char*)ws;                          // 4 MB
    signed char* sQ = (signed char*)(ws + (size_t)NROWS * DIM);  // 4 MB
    char* p = ws + (size_t)NROWS * DIM * 2;
    float* diag = (float*)p;                // 32 KB
    float* lw2 = (float*)(p + 32768);       // 32 KB
    float* lsum = (float*)(p + 65536);      // 32 KB

    norm_kernel<<<NROWS / 4, 256, 0, stream>>>(A, S, labels, aQ, sQ, diag, lw2, lsum);
    lse_gemm<<<512, 512, 0, stream>>>(aQ, sQ, lw2, lsum);
    finalize_kernel<<<1, 1024, 0, stream>>>(lsum, diag, labels, out);
}

// Round 17
// 65.047 us; speedup vs baseline: 1.1957x; 1.0276x over previous
//
#include <hip/hip_runtime.h>
#include <math.h>

#define NROWS 8192
#define DIM 512
#define INV_T 20.0f
#define QS 500.0f
// dequant * 1/T * log2(e), for exp2-based softmax accumulation
#define DEQ2 (INV_T * 1.4426950408889634f / (QS * QS))

typedef __attribute__((ext_vector_type(4))) int i32x4;

__device__ __forceinline__ void gload_lds16(const void* g, void* l) {
    __builtin_amdgcn_global_load_lds(
        (const __attribute__((address_space(1))) unsigned int*)g,
        (__attribute__((address_space(3))) unsigned int*)l, 16, 0, 0);
}

__device__ __forceinline__ void block_bar() {
    asm volatile("" ::: "memory");
    __builtin_amdgcn_s_barrier();
    asm volatile("" ::: "memory");
}

__device__ __forceinline__ float hw_exp2(float x) {
    float r;
    asm("v_exp_f32 %0, %1" : "=v"(r) : "v"(x));  // D = 2^S0, 1 inst
    return r;
}

__device__ __forceinline__ float dot4(float4 a, float4 b) {
    return a.x * b.x + a.y * b.y + a.z * b.z + a.w * b.w;
}

__device__ __forceinline__ int q4(float4 v, float s) {
    int b0 = __float2int_rn(fminf(fmaxf(v.x * s, -127.f), 127.f)) & 255;
    int b1 = __float2int_rn(fminf(fmaxf(v.y * s, -127.f), 127.f)) & 255;
    int b2 = __float2int_rn(fminf(fmaxf(v.z * s, -127.f), 127.f)) & 255;
    int b3 = __float2int_rn(fminf(fmaxf(v.w * s, -127.f), 127.f)) & 255;
    return b0 | (b1 << 8) | (b2 << 16) | (b3 << 24);
}

// One wave per row: L2-normalize, quantize to i8 (scale QS), exact fp32 diag,
// column log2-weights (0 or 1), zero row-sum accumulator.
__global__ __launch_bounds__(256) void norm_kernel(
    const float* __restrict__ A, const float* __restrict__ S,
    const int* __restrict__ labels, signed char* __restrict__ aQ,
    signed char* __restrict__ sQ, float* __restrict__ diag,
    float* __restrict__ lw2, float* __restrict__ lsum) {
    const int wave = threadIdx.x >> 6, lane = threadIdx.x & 63;
    const int row = blockIdx.x * 4 + wave;
    const float4* a4 = (const float4*)(A + (size_t)row * DIM);
    const float4* s4 = (const float4*)(S + (size_t)row * DIM);
    float4 a0 = a4[lane], a1 = a4[lane + 64];
    float4 s0 = s4[lane], s1 = s4[lane + 64];
    float saa = dot4(a0, a0) + dot4(a1, a1);
    float sss = dot4(s0, s0) + dot4(s1, s1);
    float sas = dot4(a0, s0) + dot4(a1, s1);
    for (int m = 1; m < 64; m <<= 1) {
        saa += __shfl_xor(saa, m);
        sss += __shfl_xor(sss, m);
        sas += __shfl_xor(sas, m);
    }
    const float ra = rsqrtf(saa), rs = rsqrtf(sss);
    signed char* arow = aQ + (size_t)row * DIM;
    signed char* srow = sQ + (size_t)row * DIM;
    *(int*)(arow + lane * 4)       = q4(a0, ra * QS);
    *(int*)(arow + 256 + lane * 4) = q4(a1, ra * QS);
    *(int*)(srow + lane * 4)       = q4(s0, rs * QS);
    *(int*)(srow + 256 + lane * 4) = q4(s1, rs * QS);
    if (lane == 0) {
        diag[row] = sas * ra * rs * INV_T;
        // Uniform column weighting (incl. diagonal) is exact for the final
        // loss: only label==1 rows' lse is consumed, and those rows' diagonal
        // column has log_w==0 in the reference anyway. log2-weight: 0 or 1.
        lw2[row] = (labels[row] == 0) ? 1.0f : 0.0f;
        lsum[row] = 0.0f;
    }
}

// ---------------------------------------------------------------------------
// Phased i8 GEMM + exp2 + row-sum (v17 = r10 chassis with BK=128: HALVED
// convoy count). Fitted model across r10/r12/r14/r16 (all 32 steps, all
// ~51 us): per-step wall 3825 cyc = MFMA 1178 + LDS ~1540 (overlappable) +
// ~2300 un-attributed convoy overhead -> 32 steps ~ 30 us of convoy.
// Single change: 16 steps of BK=128 (4 per ct), 2 x 64 KB LDS dbuf,
// 4 gloads/thread/step, vmcnt(4). Inner step = 2 x {8 ds_read -> lgkm ->
// 16 MFMA} inside ONE barrier pair. 8-slot XOR involution (same verified
// family at width 8; bank = f(slot) only -> 2 lanes/bank-group = free).
// 1024 thr = 16 waves (4x4, wave 64x64), grid 256 = 1 block/CU, 2D XCD map.
// ---------------------------------------------------------------------------
__global__ __launch_bounds__(1024, 4) void lse_gemm(
    const signed char* __restrict__ Aq, const signed char* __restrict__ Bq,
    const float* __restrict__ lw2, float* __restrict__ lsum) {
    __shared__ __align__(16) char lds[131072];
    // buf stride 65536: A 32 KB @0 (256 rows x 128 B), B 32 KB @32768

    const int bid = blockIdx.x;  // 256 blocks = 1 per CU
    const int xcd = bid & 7, idx = bid >> 3;     // bid%8 -> XCD
    const int rt = (xcd >> 1) * 8 + (idx & 7);   // 0..31 (256-row tile)
    const int ctg = (xcd & 1) * 4 + (idx >> 3);  // 0..7 (1024-col group)
    const int row0 = rt * 256;
    const int colg = ctg * 1024;

    const int tid = threadIdx.x;
    const int wid = tid >> 6, lane = tid & 63;
    const int wr = wid >> 2, wc = wid & 3;  // 4x4 wave grid (64x64 each)
    const int fr = lane & 15, grp = lane >> 4;
    const int f7 = fr & 7;

    // staging: thread t covers row t>>3 (halves at +128 rows), phys slot
    // t&7 (8 x 16B slots per 128-B row); fetch logical slot
    // (t&7)^(row&7) = (t&7)^((t>>3)&7)  [8-slot involution; +128 preserves
    // row&7]. Same both-sides family as the r3/r4-verified 4-slot version.
    const int sl = (tid & 7) ^ ((tid >> 3) & 7);
    const signed char* aSrc = Aq + (size_t)(row0 + (tid >> 3)) * DIM + sl * 16;
    const signed char* bSrc = Bq + (size_t)(colg + (tid >> 3)) * DIM + sl * 16;
    char* dstA = lds + tid * 16;          // + buf*65536 (+16384 rows 128+)
    char* dstB = lds + 32768 + tid * 16;  // + buf*65536 (+16384 cols 128+)

    // K-step TT (0..15): ct = TT>>2, k = TT&3 (BK=128 -> byte off k*128).
    // 4 loads per thread per step (A lo/hi, B lo/hi).
#define STAGE(buf, TT)                                                        \
    do {                                                                      \
        const int ct_ = (TT) >> 2, k_ = (TT) & 3;                             \
        gload_lds16(aSrc + k_ * 128,                     dstA + (buf) * 65536); \
        gload_lds16(aSrc + 65536 + k_ * 128,             dstA + (buf) * 65536 + 16384); \
        gload_lds16(bSrc + ct_ * 131072 + k_ * 128,      dstB + (buf) * 65536); \
        gload_lds16(bSrc + ct_ * 131072 + 65536 + k_ * 128, dstB + (buf) * 65536 + 16384); \
    } while (0)

    // fragment reads: A row R = wr*64 + m*16 + fr at byte R*128; k-slice ks
    // (0/1) slot = ks*4+grp, swizzled phys = (ks*4+grp)^(R&7) = ..^f7.
    const char* rdA = lds + (wr * 64 + fr) * 128;
    const char* rdB = lds + 32768 + (wc * 64 + fr) * 128;

    STAGE(0, 0);

    i32x4 acc[4][4] = {};
#pragma unroll 1
    for (int T = 0; T < 16; ++T) {
        const int buf = T & 1;
        if (T < 15) {
            STAGE(buf ^ 1, T + 1);
            asm volatile("s_waitcnt vmcnt(4)" ::: "memory");  // T's 4 landed
        } else {
            asm volatile("s_waitcnt vmcnt(0)" ::: "memory");
        }
        block_bar();  // buf(T) staged by all waves

        const char* bA = rdA + buf * 65536;
        const char* bB = rdB + buf * 65536;
#pragma unroll
        for (int ks = 0; ks < 2; ++ks) {
            const int psk = ((ks * 4 + grp) ^ f7) << 4;
            i32x4 a[4], b[4];
#pragma unroll
            for (int m = 0; m < 4; ++m)
                a[m] = *(const i32x4*)(bA + m * 2048 + psk);
#pragma unroll
            for (int n = 0; n < 4; ++n)
                b[n] = *(const i32x4*)(bB + n * 2048 + psk);
            asm volatile("s_waitcnt lgkmcnt(0)" ::: "memory");
            __builtin_amdgcn_sched_barrier(0);  // rule 18
            __builtin_amdgcn_s_setprio(1);
#pragma unroll
            for (int m = 0; m < 4; ++m)
#pragma unroll
                for (int n = 0; n < 4; ++n)
                    acc[m][n] = __builtin_amdgcn_mfma_i32_16x16x64_i8(
                        a[m], b[n], acc[m][n], 0, 0, 0);
            __builtin_amdgcn_s_setprio(0);
        }

        if ((T & 3) == 3) {
            // register-lean in-cage epilogue (r10/r12-proven): dequant ->
            // exp2 -> 16-lane reduce -> atomicAdd; then re-zero acc.
            const int ct = T >> 2;
            const int col0 = colg + ct * 256 + wc * 64;
            float lwv[4];
#pragma unroll
            for (int n = 0; n < 4; ++n)
                lwv[n] = lw2[col0 + n * 16 + fr];
#pragma unroll
            for (int m = 0; m < 4; ++m)
#pragma unroll
                for (int j = 0; j < 4; ++j) {
                    float s = 0.f;
#pragma unroll
                    for (int n = 0; n < 4; ++n)
                        s += hw_exp2(fmaf((float)acc[m][n][j], DEQ2, lwv[n]));
                    s += __shfl_xor(s, 1);
                    s += __shfl_xor(s, 2);
                    s += __shfl_xor(s, 4);
                    s += __shfl_xor(s, 8);
                    if (fr == 0)
                        atomicAdd(&lsum[row0 + wr * 64 + m * 16 + grp * 4 + j], s);
                }
#pragma unroll
            for (int m = 0; m < 4; ++m)
#pragma unroll
                for (int n = 0; n < 4; ++n)
                    acc[m][n] = i32x4{0, 0, 0, 0};
        }
        block_bar();  // buf(T) reads done before it is re-staged
    }
#undef STAGE
}

// 1024 threads, single block: final scalar reduction.
__global__ __launch_bounds__(1024) void finalize_kernel(
    const float* __restrict__ lsum, const float* __restrict__ diag,
    const int* __restrict__ labels, float* __restrict__ out) {
    const int tid = threadIdx.x;
    float sl = 0.f, sd = 0.f, mx = -1e9f;
    int np_ = 0, nn_ = 0;
#pragma unroll
    for (int i = tid; i < NROWS; i += 1024) {
        const float dg = diag[i];
        if (labels[i] == 1) {
            sl += logf(lsum[i]) - dg;
            sd += dg;
            np_++;
        } else {
            nn_++;
            mx = fmaxf(mx, dg);
        }
    }
    for (int m = 1; m < 64; m <<= 1) {
        sl += __shfl_xor(sl, m);
        sd += __shfl_xor(sd, m);
        mx = fmaxf(mx, __shfl_xor(mx, m));
        np_ += __shfl_xor(np_, m);
        nn_ += __shfl_xor(nn_, m);
    }
    __shared__ float rsl[16], rsd[16], rmx[16];
    __shared__ int rnp[16], rnn[16];
    const int wave = tid >> 6, lane = tid & 63;
    if (lane == 0) {
        rsl[wave] = sl; rsd[wave] = sd; rmx[wave] = mx;
        rnp[wave] = np_; rnn[wave] = nn_;
    }
    __syncthreads();
    if (tid == 0) {
        float SL = 0.f, SD = 0.f, MX = -1e9f;
        int NP = 0, NN = 0;
        for (int w = 0; w < 16; w++) {
            SL += rsl[w]; SD += rsd[w]; MX = fmaxf(MX, rmx[w]);
            NP += rnp[w]; NN += rnn[w];
        }
        const float infonce = SL / (float)NP;
        const float meanpos = SD / (float)NP;
        float pen = fmaxf(MX - meanpos + 0.2f, 0.0f);
        if (NN == 0) pen = 0.0f;
        out[0] = infonce + pen;
    }
}

extern "C" void kernel_launch(void* const* d_in, const int* in_sizes, int n_in,
                              void* d_out, int out_size, void* d_ws, size_t ws_size,
                              hipStream_t stream) {
    const float* A = (const float*)d_in[0];
    const float* S = (const float*)d_in[1];
    const int* labels = (const int*)d_in[2];
    float* out = (float*)d_out;

    char* ws = (char*)d_ws;
    signed char* aQ = (signed char*)ws;                          // 4 MB
    signed char* sQ = (signed char*)(ws + (size_t)NROWS * DIM);  // 4 MB
    char* p = ws + (size_t)NROWS * DIM * 2;
    float* diag = (float*)p;                // 32 KB
    float* lw2 = (float*)(p + 32768);       // 32 KB
    float* lsum = (float*)(p + 65536);      // 32 KB

    norm_kernel<<<NROWS / 4, 256, 0, stream>>>(A, S, labels, aQ, sQ, diag, lw2, lsum);
    lse_gemm<<<256, 1024, 0, stream>>>(aQ, sQ, lw2, lsum);
    finalize_kernel<<<1, 1024, 0, stream>>>(lsum, diag, labels, out);
}

// Round 18
// 55.804 us; speedup vs baseline: 1.3937x; 1.1656x over previous
//
#include <hip/hip_runtime.h>
#include <math.h>

#define NROWS 8192
#define DIM 512
#define INV_T 20.0f
#define QS 500.0f
// dequant * 1/T * log2(e), for exp2-based softmax accumulation
#define DEQ2 (INV_T * 1.4426950408889634f / (QS * QS))

typedef __attribute__((ext_vector_type(4))) int i32x4;

__device__ __forceinline__ void gload_lds16(const void* g, void* l) {
    __builtin_amdgcn_global_load_lds(
        (const __attribute__((address_space(1))) unsigned int*)g,
        (__attribute__((address_space(3))) unsigned int*)l, 16, 0, 0);
}

__device__ __forceinline__ void block_bar() {
    asm volatile("" ::: "memory");
    __builtin_amdgcn_s_barrier();
    asm volatile("" ::: "memory");
}

__device__ __forceinline__ float hw_exp2(float x) {
    float r;
    asm("v_exp_f32 %0, %1" : "=v"(r) : "v"(x));  // D = 2^S0, 1 inst
    return r;
}

__device__ __forceinline__ float dot4(float4 a, float4 b) {
    return a.x * b.x + a.y * b.y + a.z * b.z + a.w * b.w;
}

__device__ __forceinline__ int q4(float4 v, float s) {
    int b0 = __float2int_rn(fminf(fmaxf(v.x * s, -127.f), 127.f)) & 255;
    int b1 = __float2int_rn(fminf(fmaxf(v.y * s, -127.f), 127.f)) & 255;
    int b2 = __float2int_rn(fminf(fmaxf(v.z * s, -127.f), 127.f)) & 255;
    int b3 = __float2int_rn(fminf(fmaxf(v.w * s, -127.f), 127.f)) & 255;
    return b0 | (b1 << 8) | (b2 << 16) | (b3 << 24);
}

// One wave per row: L2-normalize, quantize to i8 (scale QS), exact fp32 diag,
// column log2-weights (0 or 1).
__global__ __launch_bounds__(256) void norm_kernel(
    const float* __restrict__ A, const float* __restrict__ S,
    const int* __restrict__ labels, signed char* __restrict__ aQ,
    signed char* __restrict__ sQ, float* __restrict__ diag,
    float* __restrict__ lw2) {
    const int wave = threadIdx.x >> 6, lane = threadIdx.x & 63;
    const int row = blockIdx.x * 4 + wave;
    const float4* a4 = (const float4*)(A + (size_t)row * DIM);
    const float4* s4 = (const float4*)(S + (size_t)row * DIM);
    float4 a0 = a4[lane], a1 = a4[lane + 64];
    float4 s0 = s4[lane], s1 = s4[lane + 64];
    float saa = dot4(a0, a0) + dot4(a1, a1);
    float sss = dot4(s0, s0) + dot4(s1, s1);
    float sas = dot4(a0, s0) + dot4(a1, s1);
    for (int m = 1; m < 64; m <<= 1) {
        saa += __shfl_xor(saa, m);
        sss += __shfl_xor(sss, m);
        sas += __shfl_xor(sas, m);
    }
    const float ra = rsqrtf(saa), rs = rsqrtf(sss);
    signed char* arow = aQ + (size_t)row * DIM;
    signed char* srow = sQ + (size_t)row * DIM;
    *(int*)(arow + lane * 4)       = q4(a0, ra * QS);
    *(int*)(arow + 256 + lane * 4) = q4(a1, ra * QS);
    *(int*)(srow + lane * 4)       = q4(s0, rs * QS);
    *(int*)(srow + 256 + lane * 4) = q4(s1, rs * QS);
    if (lane == 0) {
        diag[row] = sas * ra * rs * INV_T;
        // Uniform column weighting (incl. diagonal) is exact for the final
        // loss: only label==1 rows' lse is consumed, and those rows' diagonal
        // column has log_w==0 in the reference anyway. log2-weight: 0 or 1.
        lw2[row] = (labels[row] == 0) ? 1.0f : 0.0f;
    }
}

// ---------------------------------------------------------------------------
// Deterministic row compaction (prefix scan, no atomics -> bit-reproducible).
// perm[c] = c-th row with label==1; pad to 256-multiple with row 0 (their
// lsum slots are never consumed). meta[0]=npos, meta[1]=rtiles. Zeroes lsum.
// ---------------------------------------------------------------------------
__global__ __launch_bounds__(1024) void compact_kernel(
    const int* __restrict__ labels, int* __restrict__ perm,
    float* __restrict__ lsum, int* __restrict__ meta) {
    const int tid = threadIdx.x;
    for (int i = tid; i < 8448; i += 1024) {
        perm[i] = 0;
        lsum[i] = 0.f;
    }
    __syncthreads();
    const int lane = tid & 63, wid = tid >> 6;
    int lab[8], cnt = 0;
#pragma unroll
    for (int i = 0; i < 8; ++i) {
        lab[i] = labels[tid * 8 + i];
        cnt += (lab[i] == 1);
    }
    int inc = cnt;
    for (int d = 1; d < 64; d <<= 1) {
        int v = __shfl_up(inc, d);
        if (lane >= d) inc += v;
    }
    __shared__ int wsum[16], wpre[16];
    if (lane == 63) wsum[wid] = inc;
    __syncthreads();
    if (tid == 0) {
        int acc = 0;
        for (int w = 0; w < 16; ++w) { acc += wsum[w]; wpre[w] = acc; }
    }
    __syncthreads();
    int off = (wid ? wpre[wid - 1] : 0) + inc - cnt;  // exclusive prefix
#pragma unroll
    for (int i = 0; i < 8; ++i)
        if (lab[i] == 1) perm[off++] = tid * 8 + i;
    if (tid == 0) {
        meta[0] = wpre[15];
        meta[1] = (wpre[15] + 255) >> 8;  // active 256-row tiles
    }
}

// ---------------------------------------------------------------------------
// Phased i8 GEMM + exp2 + row-sum over POSITIVE ROWS ONLY (v18 = r12 chassis
// + perm row-gather). Reference consumes lse only where label==1 (~N/2):
// negative rows need only their diag (computed in norm). ~2x FLOP cut.
// Grid fixed at 512 (graph-safe); rt = bid>>4, ctg = bid&15; blocks with
// rt >= meta.rtiles exit immediately -> active ~256 contiguous bids spread
// ~1/CU. Chassis byte-identical to r12 (51 us, VGPR 60, 2 blocks/CU):
// 512 thr = 8 waves (4x2), tile 256 compact-rows x 512 cols (4-ct sweep),
// 48 KB LDS dbuf, vmcnt(3), verified 4-slot involution swizzles, register-
// lean in-cage epilogue.
// ---------------------------------------------------------------------------
__global__ __launch_bounds__(512, 4) void lse_gemm(
    const signed char* __restrict__ Aq, const signed char* __restrict__ Bq,
    const float* __restrict__ lw2, const int* __restrict__ perm,
    const int* __restrict__ meta, float* __restrict__ lsum) {
    __shared__ __align__(16) char lds[49152];
    // buf layout (stride 24576): A 16 KB @0, B 8 KB @16384

    const int bid = blockIdx.x;  // 512 blocks
    const int rt = bid >> 4, ctg = bid & 15;
    if (rt >= meta[1]) return;  // inactive row-tile (input-deterministic)
    const int row0 = rt * 256;  // compact-row base
    const int colg = ctg * 512;

    const int tid = threadIdx.x;
    const int wid = tid >> 6, lane = tid & 63;
    const int wr = wid >> 1, wc = wid & 1;  // 4x2 wave grid (64x64 each)
    const int fr = lane & 15, grp = lane >> 4;

    // staging: thread t -> compact row t>>2 (+128 second half), phys slot
    // t&3; fetch logical slot (t&3)^((t>>3)&3) [4-slot involution, verified;
    // swizzle lives in the k-slot dim -> unaffected by row gather].
    const int sl = (tid & 3) ^ ((tid >> 3) & 3);
    const int r0 = perm[row0 + (tid >> 2)];
    const int r1 = perm[row0 + 128 + (tid >> 2)];
    const signed char* aSrc0 = Aq + (size_t)r0 * DIM + sl * 16;
    const signed char* aSrc1 = Aq + (size_t)r1 * DIM + sl * 16;
    const signed char* bSrc = Bq + (size_t)(colg + (tid >> 2)) * DIM + sl * 16;
    char* dstA = lds + tid * 16;          // + buf*24576 (+8192 rows 128+)
    char* dstB = lds + 16384 + tid * 16;  // + buf*24576

    // K-step TT (0..31): ct = TT>>3, k = TT&7. 3 loads per thread per step.
#define STAGE(buf, TT)                                                        \
    do {                                                                      \
        const int ct_ = (TT) >> 3, k_ = (TT) & 7;                             \
        gload_lds16(aSrc0 + k_ * 64,              dstA + (buf) * 24576);      \
        gload_lds16(aSrc1 + k_ * 64,              dstA + (buf) * 24576 + 8192); \
        gload_lds16(bSrc + ct_ * 65536 + k_ * 64, dstB + (buf) * 24576);      \
    } while (0)

    // fragment reads: A row R = wr*64 + m*16 + fr at byte R*64 + ps;
    // B row = wc*64 + n*16 + fr. ps = (grp ^ ((fr>>1)&3))*16.
    const int ps = (grp ^ ((fr >> 1) & 3)) << 4;
    const char* rdA = lds + (wr * 64 + fr) * 64 + ps;
    const char* rdB = lds + 16384 + (wc * 64 + fr) * 64 + ps;

    STAGE(0, 0);

    i32x4 acc[4][4] = {};
#pragma unroll 2
    for (int T = 0; T < 32; ++T) {
        const int buf = T & 1;
        if (T < 31) {
            STAGE(buf ^ 1, T + 1);
            asm volatile("s_waitcnt vmcnt(3)" ::: "memory");
        } else {
            asm volatile("s_waitcnt vmcnt(0)" ::: "memory");
        }
        block_bar();  // buf(T) staged by all waves

        i32x4 a[4], b[4];
#pragma unroll
        for (int m = 0; m < 4; ++m)
            a[m] = *(const i32x4*)(rdA + buf * 24576 + m * 1024);
#pragma unroll
        for (int n = 0; n < 4; ++n)
            b[n] = *(const i32x4*)(rdB + buf * 24576 + n * 1024);
        asm volatile("s_waitcnt lgkmcnt(0)" ::: "memory");
        __builtin_amdgcn_sched_barrier(0);  // rule 18: pin MFMA after lgkm

        __builtin_amdgcn_s_setprio(1);
#pragma unroll
        for (int m = 0; m < 4; ++m)
#pragma unroll
            for (int n = 0; n < 4; ++n)
                acc[m][n] = __builtin_amdgcn_mfma_i32_16x16x64_i8(
                    a[m], b[n], acc[m][n], 0, 0, 0);
        __builtin_amdgcn_s_setprio(0);

        if ((T & 7) == 7) {
            // register-lean in-cage epilogue (r10/r12-proven): dequant ->
            // exp2 -> 16-lane reduce -> atomicAdd into compact lsum slot.
            const int ct = T >> 3;
            const int col0 = colg + ct * 128 + wc * 64;
            float lwv[4];
#pragma unroll
            for (int n = 0; n < 4; ++n)
                lwv[n] = lw2[col0 + n * 16 + fr];
#pragma unroll
            for (int m = 0; m < 4; ++m)
#pragma unroll
                for (int j = 0; j < 4; ++j) {
                    float s = 0.f;
#pragma unroll
                    for (int n = 0; n < 4; ++n)
                        s += hw_exp2(fmaf((float)acc[m][n][j], DEQ2, lwv[n]));
                    s += __shfl_xor(s, 1);
                    s += __shfl_xor(s, 2);
                    s += __shfl_xor(s, 4);
                    s += __shfl_xor(s, 8);
                    if (fr == 0)
                        atomicAdd(&lsum[row0 + wr * 64 + m * 16 + grp * 4 + j], s);
                }
#pragma unroll
            for (int m = 0; m < 4; ++m)
#pragma unroll
                for (int n = 0; n < 4; ++n)
                    acc[m][n] = i32x4{0, 0, 0, 0};
        }
        block_bar();  // buf(T) reads done before overwrite
    }
#undef STAGE
}

// 1024 threads, single block: final scalar reduction.
// Positive terms via perm gather; negative max over original diag.
__global__ __launch_bounds__(1024) void finalize_kernel(
    const float* __restrict__ lsum, const float* __restrict__ diag,
    const int* __restrict__ labels, const int* __restrict__ perm,
    const int* __restrict__ meta, float* __restrict__ out) {
    const int tid = threadIdx.x;
    const int npos = meta[0];
    float sl = 0.f, sd = 0.f, mx = -1e9f;
    int nn_ = 0;
    for (int c = tid; c < npos; c += 1024) {
        const int r = perm[c];
        const float dg = diag[r];
        sl += logf(lsum[c]) - dg;
        sd += dg;
    }
    for (int i = tid; i < NROWS; i += 1024) {
        if (labels[i] == 0) {
            nn_++;
            mx = fmaxf(mx, diag[i]);
        }
    }
    for (int m = 1; m < 64; m <<= 1) {
        sl += __shfl_xor(sl, m);
        sd += __shfl_xor(sd, m);
        mx = fmaxf(mx, __shfl_xor(mx, m));
        nn_ += __shfl_xor(nn_, m);
    }
    __shared__ float rsl[16], rsd[16], rmx[16];
    __shared__ int rnn[16];
    const int wave = tid >> 6, lane = tid & 63;
    if (lane == 0) {
        rsl[wave] = sl; rsd[wave] = sd; rmx[wave] = mx; rnn[wave] = nn_;
    }
    __syncthreads();
    if (tid == 0) {
        float SL = 0.f, SD = 0.f, MX = -1e9f;
        int NN = 0;
        for (int w = 0; w < 16; w++) {
            SL += rsl[w]; SD += rsd[w]; MX = fmaxf(MX, rmx[w]); NN += rnn[w];
        }
        const float infonce = SL / (float)npos;
        const float meanpos = SD / (float)npos;
        float pen = fmaxf(MX - meanpos + 0.2f, 0.0f);
        if (NN == 0) pen = 0.0f;
        out[0] = infonce + pen;
    }
}

extern "C" void kernel_launch(void* const* d_in, const int* in_sizes, int n_in,
                              void* d_out, int out_size, void* d_ws, size_t ws_size,
                              hipStream_t stream) {
    const float* A = (const float*)d_in[0];
    const float* S = (const float*)d_in[1];
    const int* labels = (const int*)d_in[2];
    float* out = (float*)d_out;

    char* ws = (char*)d_ws;
    signed char* aQ = (signed char*)ws;                          // 4 MB
    signed char* sQ = (signed char*)(ws + (size_t)NROWS * DIM);  // 4 MB
    char* p = ws + (size_t)NROWS * DIM * 2;
    float* diag = (float*)p;                   // 32 KB
    float* lw2 = (float*)(p + 32768);          // 32 KB
    float* lsum = (float*)(p + 65536);         // 8448 floats (36 KB slot)
    int* perm = (int*)(p + 65536 + 36864);     // 8448 ints (36 KB slot)
    int* meta = (int*)(p + 65536 + 73728);     // 2 ints

    norm_kernel<<<NROWS / 4, 256, 0, stream>>>(A, S, labels, aQ, sQ, diag, lw2);
    compact_kernel<<<1, 1024, 0, stream>>>(labels, perm, lsum, meta);
    lse_gemm<<<512, 512, 0, stream>>>(aQ, sQ, lw2, perm, meta, lsum);
    finalize_kernel<<<1, 1024, 0, stream>>>(lsum, diag, labels, perm, meta, out);
}